// Round 1
// baseline (432.470 us; speedup 1.0000x reference)
//
#include <hip/hip_runtime.h>

// RESCAL hinge loss on MI355X.
// E=1e6 entities (D=64), R=1000 relations (64x64), B=32768 samples.
// score(h,t,r) = (1/64) * h^T R_r t ; out = sum_b max(0, sn - sp + 1).
//
// Strategy: one 64-lane wave per sample, computes both pos and neg scores.
// Lane k keeps t[4*(k&15)..+3] (float4) and h[k] in registers; the 64x64
// relation matrix is streamed with 16 coalesced global_load_dwordx4 per side
// (1 KiB per wave-instruction). h broadcast via __shfl (ds_bpermute).
// Rel matrices total 16.4 MB -> L2/L3 resident; this kernel is cache-BW bound.

#define DIM 64
#define BATCH 32768

__device__ __forceinline__ float wave_reduce_sum(float v) {
    #pragma unroll
    for (int off = 32; off > 0; off >>= 1)
        v += __shfl_xor(v, off, 64);
    return v;
}

__device__ __forceinline__ float score_one(const float* __restrict__ ent,
                                           const float* __restrict__ rel,
                                           int h_idx, int t_idx, int r_idx,
                                           int lane) {
    // t fragment: lane k needs t[4*(k&15) .. 4*(k&15)+3]
    const float4* t4p = (const float4*)(ent + (size_t)t_idx * DIM);
    float4 t4 = t4p[lane & 15];
    // h fragment: lane k holds h[k]; broadcast later via shuffle
    float hv = ent[(size_t)h_idx * DIM + lane];

    const float4* r4 = (const float4*)(rel + (size_t)r_idx * (DIM * DIM));
    const int quad = lane >> 4;
    float acc = 0.f;
    #pragma unroll
    for (int s = 0; s < 16; ++s) {
        // iteration s covers elements [s*256, s*256+256) of R_r:
        // lane k, component c -> row i = 4*s + (k>>4), col j = 4*(k&15)+c
        float4 rv = r4[s * 64 + lane];
        float part = rv.x * t4.x + rv.y * t4.y + rv.z * t4.z + rv.w * t4.w;
        float hb = __shfl(hv, s * 4 + quad, 64);
        acc = fmaf(part, hb, acc);
    }
    acc = wave_reduce_sum(acc);
    return acc * (1.0f / DIM);
}

__global__ __launch_bounds__(256) void rescal_hinge_kernel(
    const float* __restrict__ ent, const float* __restrict__ rel,
    const int* __restrict__ ph, const int* __restrict__ pt,
    const int* __restrict__ pr, const int* __restrict__ nh,
    const int* __restrict__ nt, const int* __restrict__ nr,
    float* __restrict__ out)
{
    const int warp = threadIdx.x >> 6;
    const int lane = threadIdx.x & 63;
    const int b = blockIdx.x * 4 + warp;

    __shared__ float red[4];
    float hinge = 0.f;
    if (b < BATCH) {
        float sp = score_one(ent, rel, ph[b], pt[b], pr[b], lane);
        float sn = score_one(ent, rel, nh[b], nt[b], nr[b], lane);
        hinge = fmaxf(0.f, sn - sp + 1.0f);
    }
    if (lane == 0) red[warp] = hinge;
    __syncthreads();
    if (threadIdx.x == 0) {
        atomicAdd(out, red[0] + red[1] + red[2] + red[3]);
    }
}

extern "C" void kernel_launch(void* const* d_in, const int* in_sizes, int n_in,
                              void* d_out, int out_size, void* d_ws, size_t ws_size,
                              hipStream_t stream) {
    const float* ent = (const float*)d_in[0];
    const float* rel = (const float*)d_in[1];
    const int* ph = (const int*)d_in[2];
    const int* pt = (const int*)d_in[3];
    const int* pr = (const int*)d_in[4];
    const int* nh = (const int*)d_in[5];
    const int* nt = (const int*)d_in[6];
    const int* nr = (const int*)d_in[7];
    float* out = (float*)d_out;

    hipMemsetAsync(out, 0, sizeof(float), stream);
    dim3 grid(BATCH / 4);  // 4 waves per block, 1 sample per wave
    rescal_hinge_kernel<<<grid, 256, 0, stream>>>(ent, rel, ph, pt, pr,
                                                  nh, nt, nr, out);
}

// Round 2
// 427.313 us; speedup vs baseline: 1.0121x; 1.0121x over previous
//
#include <hip/hip_runtime.h>

// RESCAL hinge loss on MI355X — relation-binned version.
// E=1e6 entities (D=64), R=1000 relations (64x64), B=32768 samples.
// score(h,t,r) = (1/64) * h^T R_r t ; out = sum_b max(0, sn - sp + 1).
//
// R1 lesson: per-task streaming of R_r = 1.07 GB of L3 traffic -> 432 us.
// R2: bin the 65536 (sample,side) tasks by relation id; one block per
// relation loads R_r into LDS once and serves ~65 tasks from LDS,
// 4 tasks per wave per chunk-read to amortize LDS bandwidth.

#define DIM 64
#define BATCH 32768
#define NREL 1000
#define NTASK (2 * BATCH)          // pos + neg sides
#define RPAD 1024                  // counts/offsets padded to pow2
#define LDS_STRIDE4 17             // float4 stride per row (68 floats): bank-optimal

// ---- workspace layout (bytes) ----
// [0      , 4096 )  counts[1024]   (zeroed each call)
// [4096   , 8192 )  cursors[1024]  (zeroed each call)
// [8192   , 12288)  offsets[1024]
// [12288  , 274432) bins[65536]
// [274432 , 536576) scores[65536]  (task = side<<15 | b)

__global__ __launch_bounds__(256) void hist_kernel(
    const int* __restrict__ pr, const int* __restrict__ nr,
    int* __restrict__ counts)
{
    int t = blockIdx.x * 256 + threadIdx.x;   // 0..65535
    int b = t & (BATCH - 1);
    int r = (t >> 15) ? nr[b] : pr[b];
    atomicAdd(&counts[r], 1);
}

__global__ __launch_bounds__(1024) void scan_kernel(
    const int* __restrict__ counts, int* __restrict__ offsets)
{
    __shared__ int tmp[RPAD];
    int i = threadIdx.x;
    int v = counts[i];
    tmp[i] = v;
    __syncthreads();
    #pragma unroll
    for (int d = 1; d < RPAD; d <<= 1) {
        int add = (i >= d) ? tmp[i - d] : 0;
        __syncthreads();
        tmp[i] += add;
        __syncthreads();
    }
    offsets[i] = tmp[i] - v;   // exclusive prefix
}

__global__ __launch_bounds__(256) void scatter_kernel(
    const int* __restrict__ pr, const int* __restrict__ nr,
    const int* __restrict__ offsets, int* __restrict__ cursors,
    int* __restrict__ bins)
{
    int t = blockIdx.x * 256 + threadIdx.x;
    int b = t & (BATCH - 1);
    int r = (t >> 15) ? nr[b] : pr[b];
    int pos = offsets[r] + atomicAdd(&cursors[r], 1);
    bins[pos] = t;
}

__global__ __launch_bounds__(256) void score_kernel(
    const float* __restrict__ ent, const float* __restrict__ rel,
    const int* __restrict__ ph, const int* __restrict__ pt,
    const int* __restrict__ nh, const int* __restrict__ nt,
    const int* __restrict__ offsets, const int* __restrict__ counts,
    const int* __restrict__ bins, float* __restrict__ scores)
{
    const int r = blockIdx.x >> 1;       // 2 blocks per relation
    const int half = blockIdx.x & 1;
    const int warp = threadIdx.x >> 6;
    const int lane = threadIdx.x & 63;

    __shared__ float4 Rsh[DIM * LDS_STRIDE4];   // padded rows: 17 float4/row

    // stage R_r: 1024 float4, coalesced; f -> row f>>4, chunk f&15
    const float4* rg = (const float4*)(rel + (size_t)r * (DIM * DIM));
    #pragma unroll
    for (int j = 0; j < 4; ++j) {
        int f = threadIdx.x + 256 * j;
        float4 v = rg[f];
        Rsh[(f >> 4) * LDS_STRIDE4 + (f & 15)] = v;
    }
    __syncthreads();

    const int start = offsets[r];
    const int end = start + counts[r];
    const int gw = half * 4 + warp;     // global wave id 0..7 for this relation

    for (int base = start + gw * 4; base < end; base += 32) {
        const int nv = min(4, end - base);
        const float* tp[4];
        float hv[4];
        int tk[4];
        #pragma unroll
        for (int m = 0; m < 4; ++m) {
            int idx = (m < nv) ? (base + m) : base;
            int t = bins[idx];
            tk[m] = t;
            int b = t & (BATCH - 1);
            int side = t >> 15;
            int hi = side ? nh[b] : ph[b];
            int ti = side ? nt[b] : pt[b];
            tp[m] = ent + (size_t)ti * DIM;
            hv[m] = ent[(size_t)hi * DIM + lane];   // lane k holds h[k]
        }
        float acc0 = 0.f, acc1 = 0.f, acc2 = 0.f, acc3 = 0.f;
        #pragma unroll
        for (int s = 0; s < 16; ++s) {
            float4 rv = Rsh[lane * LDS_STRIDE4 + s];   // row=lane, chunk s
            float4 t0 = ((const float4*)tp[0])[s];     // wave-broadcast loads
            float4 t1 = ((const float4*)tp[1])[s];
            float4 t2 = ((const float4*)tp[2])[s];
            float4 t3 = ((const float4*)tp[3])[s];
            acc0 = fmaf(rv.x, t0.x, fmaf(rv.y, t0.y, fmaf(rv.z, t0.z, fmaf(rv.w, t0.w, acc0))));
            acc1 = fmaf(rv.x, t1.x, fmaf(rv.y, t1.y, fmaf(rv.z, t1.z, fmaf(rv.w, t1.w, acc1))));
            acc2 = fmaf(rv.x, t2.x, fmaf(rv.y, t2.y, fmaf(rv.z, t2.z, fmaf(rv.w, t2.w, acc2))));
            acc3 = fmaf(rv.x, t3.x, fmaf(rv.y, t3.y, fmaf(rv.z, t3.z, fmaf(rv.w, t3.w, acc3))));
        }
        float sc[4] = { acc0 * hv[0], acc1 * hv[1], acc2 * hv[2], acc3 * hv[3] };
        #pragma unroll
        for (int m = 0; m < 4; ++m) {
            float v = sc[m];
            #pragma unroll
            for (int off = 32; off > 0; off >>= 1)
                v += __shfl_xor(v, off, 64);
            if (lane == 0 && m < nv)
                scores[tk[m]] = v * (1.0f / DIM);
        }
    }
}

__global__ __launch_bounds__(256) void hinge_kernel(
    const float* __restrict__ scores, float* __restrict__ out)
{
    int b = blockIdx.x * 256 + threadIdx.x;   // 0..32767
    float sp = scores[b];
    float sn = scores[BATCH + b];
    float v = fmaxf(0.f, sn - sp + 1.0f);
    #pragma unroll
    for (int off = 32; off > 0; off >>= 1)
        v += __shfl_xor(v, off, 64);
    __shared__ float red[4];
    int warp = threadIdx.x >> 6;
    int lane = threadIdx.x & 63;
    if (lane == 0) red[warp] = v;
    __syncthreads();
    if (threadIdx.x == 0)
        atomicAdd(out, red[0] + red[1] + red[2] + red[3]);
}

extern "C" void kernel_launch(void* const* d_in, const int* in_sizes, int n_in,
                              void* d_out, int out_size, void* d_ws, size_t ws_size,
                              hipStream_t stream) {
    const float* ent = (const float*)d_in[0];
    const float* rel = (const float*)d_in[1];
    const int* ph = (const int*)d_in[2];
    const int* pt = (const int*)d_in[3];
    const int* pr = (const int*)d_in[4];
    const int* nh = (const int*)d_in[5];
    const int* nt = (const int*)d_in[6];
    const int* nr = (const int*)d_in[7];
    float* out = (float*)d_out;

    char* ws = (char*)d_ws;
    int* counts   = (int*)(ws + 0);
    int* cursors  = (int*)(ws + 4096);
    int* offsets  = (int*)(ws + 8192);
    int* bins     = (int*)(ws + 12288);
    float* scores = (float*)(ws + 274432);

    hipMemsetAsync(ws, 0, 8192, stream);          // counts + cursors
    hipMemsetAsync(out, 0, sizeof(float), stream);

    hist_kernel<<<NTASK / 256, 256, 0, stream>>>(pr, nr, counts);
    scan_kernel<<<1, RPAD, 0, stream>>>(counts, offsets);
    scatter_kernel<<<NTASK / 256, 256, 0, stream>>>(pr, nr, offsets, cursors, bins);
    score_kernel<<<2 * NREL, 256, 0, stream>>>(ent, rel, ph, pt, nh, nt,
                                               offsets, counts, bins, scores);
    hinge_kernel<<<BATCH / 256, 256, 0, stream>>>(scores, out);
}